// Round 1
// baseline (1099.485 us; speedup 1.0000x reference)
//
#include <hip/hip_runtime.h>
#include <hip/hip_bf16.h>
#include <stdint.h>

#define IN_F   4096
#define OUT_F  11008
#define M_DIM  8192          // B*S = 4*2048

#define BM 128
#define BN 128
#define BK 64
#define TILES_M (M_DIM / BM)   // 64
#define TILES_N (OUT_F / BN)   // 86
#define NWG (TILES_M * TILES_N) // 5504 (divisible by 8 -> simple XCD swizzle bijective)

typedef __attribute__((ext_vector_type(8))) short short8;
typedef __attribute__((ext_vector_type(4))) float f32x4;

union Pack8 { __bf16 h[8]; uint4 u; };

__device__ inline uint4 pack8_f(float4 f0, float4 f1) {
    Pack8 o;
    o.h[0] = (__bf16)f0.x; o.h[1] = (__bf16)f0.y;
    o.h[2] = (__bf16)f0.z; o.h[3] = (__bf16)f0.w;
    o.h[4] = (__bf16)f1.x; o.h[5] = (__bf16)f1.y;
    o.h[6] = (__bf16)f1.z; o.h[7] = (__bf16)f1.w;
    return o.u;
}

// 4 packed int32 (one byte each: lo nibble = even idx, hi nibble = odd idx) -> 8 bf16
__device__ inline uint4 dequant8(int4 v, float s, float zb) {
    Pack8 o;
    int pv[4] = {v.x, v.y, v.z, v.w};
#pragma unroll
    for (int j = 0; j < 4; ++j) {
        o.h[2 * j]     = (__bf16)fmaf((float)(pv[j] & 15), s, zb);
        o.h[2 * j + 1] = (__bf16)fmaf((float)((pv[j] >> 4) & 15), s, zb);
    }
    return o.u;
}

// ---------- preprocessing: x fp32 -> bf16 ----------
__global__ void cvt_x_kernel(const float* __restrict__ x, uint4* __restrict__ xb, int nChunks) {
    int stride = gridDim.x * blockDim.x;
    for (int c = blockIdx.x * blockDim.x + threadIdx.x; c < nChunks; c += stride) {
        const float4* p = (const float4*)(x + (size_t)c * 8);
        xb[c] = pack8_f(p[0], p[1]);
    }
}

// ---------- preprocessing: packed int4 W -> bf16 [OUT_F][IN_F] ----------
__global__ void deq_w_kernel(const int* __restrict__ pw, const float* __restrict__ scales,
                             const int* __restrict__ zps, uint4* __restrict__ wb, int nChunks) {
    int stride = gridDim.x * blockDim.x;
    for (int c = blockIdx.x * blockDim.x + threadIdx.x; c < nChunks; c += stride) {
        int row = c >> 9;          // 512 chunks (of 4 int32) per row
        int cc  = c & 511;
        float s  = scales[row];
        float zb = -s * (float)zps[row];
        int4 v = *(const int4*)(pw + (size_t)row * (IN_F / 2) + cc * 4);
        wb[c] = dequant8(v, s, zb);   // chunk c covers elements row*4096 + cc*8 .. +7
    }
}

// ---------- GEMM: out = x * W^T + bias ----------
// 256 threads = 4 waves; wave (wm,wn) owns a 64x64 output sub-tile (4x4 frags of 16x16).
// LDS tiles [128][64] bf16 with XOR swizzle byte^=((row&7)<<4) (row stride 128B = G4 conflict case).
template <bool PREDEQ>
__global__ __launch_bounds__(256) void w4a16_gemm(
    const float* __restrict__ xf, const uint4* __restrict__ xb,
    const int* __restrict__ pw, const uint4* __restrict__ wb,
    const float* __restrict__ scales, const int* __restrict__ zps,
    const float* __restrict__ bias, float* __restrict__ out) {

    __shared__ __align__(16) __bf16 As[BM * BK];
    __shared__ __align__(16) __bf16 Bs[BN * BK];

    const int tid  = threadIdx.x;
    const int lane = tid & 63;
    const int wid  = tid >> 6;
    const int wm   = wid >> 1;   // 0..1
    const int wn   = wid & 1;    // 0..1

    // XCD-aware swizzle (NWG=5504, 5504/8=688, bijective)
    int orig = blockIdx.x;
    int wg   = (orig & 7) * (NWG / 8) + (orig >> 3);
    const int bm0 = (wg / TILES_N) * BM;
    const int bn0 = (wg % TILES_N) * BN;

    f32x4 acc[4][4];
#pragma unroll
    for (int i = 0; i < 4; ++i)
#pragma unroll
        for (int j = 0; j < 4; ++j) acc[i][j] = {0.f, 0.f, 0.f, 0.f};

    for (int kt = 0; kt < IN_F / BK; ++kt) {
        // ---- stage A: 128 rows x 64 bf16 = 1024 chunks of 16B, 4 per thread ----
#pragma unroll
        for (int i = 0; i < 4; ++i) {
            int ci  = i * 256 + tid;
            int row = ci >> 3, c8 = ci & 7;
            uint4 d;
            if (PREDEQ) {
                d = xb[(size_t)(bm0 + row) * (IN_F / 8) + kt * (BK / 8) + c8];
            } else {
                const float4* p = (const float4*)(xf + (size_t)(bm0 + row) * IN_F + kt * BK + c8 * 8);
                d = pack8_f(p[0], p[1]);
            }
            *(uint4*)((char*)As + row * (BK * 2) + ((c8 * 16) ^ ((row & 7) << 4))) = d;
        }
        // ---- stage B ----
#pragma unroll
        for (int i = 0; i < 4; ++i) {
            int ci  = i * 256 + tid;
            int row = ci >> 3, c8 = ci & 7;
            uint4 d;
            if (PREDEQ) {
                d = wb[(size_t)(bn0 + row) * (IN_F / 8) + kt * (BK / 8) + c8];
            } else {
                int r    = bn0 + row;
                float s  = scales[r];
                float zb = -s * (float)zps[r];
                int4 v = *(const int4*)(pw + (size_t)r * (IN_F / 2) + kt * (BK / 2) + c8 * 4);
                d = dequant8(v, s, zb);
            }
            *(uint4*)((char*)Bs + row * (BK * 2) + ((c8 * 16) ^ ((row & 7) << 4))) = d;
        }
        __syncthreads();

        // ---- compute: 2 k-subtiles of 32, 16 MFMA each per wave ----
#pragma unroll
        for (int kk = 0; kk < 2; ++kk) {
            short8 a[4], b[4];
#pragma unroll
            for (int mi = 0; mi < 4; ++mi) {
                int row = wm * 64 + mi * 16 + (lane & 15);
                a[mi] = *(const short8*)((const char*)As + row * (BK * 2) +
                                         ((kk * 64 + (lane >> 4) * 16) ^ ((row & 7) << 4)));
            }
#pragma unroll
            for (int ni = 0; ni < 4; ++ni) {
                int row = wn * 64 + ni * 16 + (lane & 15);
                b[ni] = *(const short8*)((const char*)Bs + row * (BK * 2) +
                                         ((kk * 64 + (lane >> 4) * 16) ^ ((row & 7) << 4)));
            }
#pragma unroll
            for (int mi = 0; mi < 4; ++mi)
#pragma unroll
                for (int ni = 0; ni < 4; ++ni)
                    acc[mi][ni] = __builtin_amdgcn_mfma_f32_16x16x32_bf16(a[mi], b[ni], acc[mi][ni], 0, 0, 0);
        }
        __syncthreads();
    }

    // ---- epilogue: C/D layout col=lane&15, row=(lane>>4)*4+r (m89-verified) ----
#pragma unroll
    for (int ni = 0; ni < 4; ++ni) {
        int col  = bn0 + wn * 64 + ni * 16 + (lane & 15);
        float bv = bias[col];
#pragma unroll
        for (int mi = 0; mi < 4; ++mi) {
            int row0 = bm0 + wm * 64 + mi * 16 + (lane >> 4) * 4;
#pragma unroll
            for (int r = 0; r < 4; ++r)
                out[(size_t)(row0 + r) * OUT_F + col] = acc[mi][ni][r] + bv;
        }
    }
}

extern "C" void kernel_launch(void* const* d_in, const int* in_sizes, int n_in,
                              void* d_out, int out_size, void* d_ws, size_t ws_size,
                              hipStream_t stream) {
    const float* x      = (const float*)d_in[0];
    const int* pw       = (const int*)d_in[1];
    const float* scales = (const float*)d_in[2];
    const int* zps      = (const int*)d_in[3];
    const float* bias   = (const float*)d_in[4];
    float* out          = (float*)d_out;

    const size_t xb_bytes = (size_t)M_DIM * IN_F * 2;   // 64 MiB
    const size_t wb_bytes = (size_t)OUT_F * IN_F * 2;   // ~86 MiB
    const bool predeq = ws_size >= xb_bytes + wb_bytes;

    dim3 grid(NWG), block(256);
    if (predeq) {
        uint4* xb = (uint4*)d_ws;
        uint4* wb = (uint4*)((char*)d_ws + xb_bytes);
        cvt_x_kernel<<<2048, 256, 0, stream>>>(x, xb, M_DIM * IN_F / 8);
        deq_w_kernel<<<2048, 256, 0, stream>>>(pw, scales, zps, wb, OUT_F * (IN_F / 8));
        w4a16_gemm<true><<<grid, block, 0, stream>>>(x, xb, pw, wb, scales, zps, bias, out);
    } else {
        w4a16_gemm<false><<<grid, block, 0, stream>>>(x, nullptr, pw, nullptr, scales, zps, bias, out);
    }
}

// Round 2
// 1076.836 us; speedup vs baseline: 1.0210x; 1.0210x over previous
//
#include <hip/hip_runtime.h>
#include <hip/hip_bf16.h>
#include <stdint.h>

#define IN_F   4096
#define OUT_F  11008
#define M_DIM  8192          // B*S = 4*2048

#define BM 128
#define BN 128
#define BK 64
#define TILES_M (M_DIM / BM)   // 64
#define TILES_N (OUT_F / BN)   // 86
#define NWG (TILES_M * TILES_N) // 5504 (divisible by 8 -> simple XCD swizzle bijective)

typedef __attribute__((ext_vector_type(8))) short short8;
typedef __attribute__((ext_vector_type(4))) float f32x4;

union Pack8 { __bf16 h[8]; uint4 u; };

__device__ inline uint4 pack8_f(float4 f0, float4 f1) {
    Pack8 o;
    o.h[0] = (__bf16)f0.x; o.h[1] = (__bf16)f0.y;
    o.h[2] = (__bf16)f0.z; o.h[3] = (__bf16)f0.w;
    o.h[4] = (__bf16)f1.x; o.h[5] = (__bf16)f1.y;
    o.h[6] = (__bf16)f1.z; o.h[7] = (__bf16)f1.w;
    return o.u;
}

// 4 packed int32 (one byte each: lo nibble = even idx, hi nibble = odd idx) -> 8 bf16
__device__ inline uint4 dequant8(int4 v, float s, float zb) {
    Pack8 o;
    int pv[4] = {v.x, v.y, v.z, v.w};
#pragma unroll
    for (int j = 0; j < 4; ++j) {
        o.h[2 * j]     = (__bf16)fmaf((float)(pv[j] & 15), s, zb);
        o.h[2 * j + 1] = (__bf16)fmaf((float)((pv[j] >> 4) & 15), s, zb);
    }
    return o.u;
}

// async global(16B/lane) -> LDS (wave-uniform base + lane*16)
#define GLOAD_LDS16(g, l)                                                     \
    __builtin_amdgcn_global_load_lds(                                         \
        (const __attribute__((address_space(1))) void*)(g),                   \
        (__attribute__((address_space(3))) void*)(l), 16, 0, 0)

// ---------- preprocessing: x fp32 -> bf16 ----------
__global__ void cvt_x_kernel(const float* __restrict__ x, uint4* __restrict__ xb, int nChunks) {
    int stride = gridDim.x * blockDim.x;
    for (int c = blockIdx.x * blockDim.x + threadIdx.x; c < nChunks; c += stride) {
        const float4* p = (const float4*)(x + (size_t)c * 8);
        xb[c] = pack8_f(p[0], p[1]);
    }
}

// ---------- preprocessing: packed int4 W -> bf16 [OUT_F][IN_F] ----------
__global__ void deq_w_kernel(const int* __restrict__ pw, const float* __restrict__ scales,
                             const int* __restrict__ zps, uint4* __restrict__ wb, int nChunks) {
    int stride = gridDim.x * blockDim.x;
    for (int c = blockIdx.x * blockDim.x + threadIdx.x; c < nChunks; c += stride) {
        int row = c >> 9;          // 512 chunks (of 4 int32) per row
        int cc  = c & 511;
        float s  = scales[row];
        float zb = -s * (float)zps[row];
        int4 v = *(const int4*)(pw + (size_t)row * (IN_F / 2) + cc * 4);
        wb[c] = dequant8(v, s, zb);
    }
}

// ---------- GEMM (predeq fast path): out = x * W^T + bias ----------
// m97 structure: 128x128 tile, BK=64, 4 waves, global_load_lds width-16 staging.
// LDS layout: [row][64] bf16 with slot swizzle (chunk c8 stored at slot c8^(row&7)).
// gload_lds writes linearly, so the swizzle is applied to the per-lane GLOBAL
// source chunk: lane l of an 8-row group loads chunk (l&7)^(l>>3) of row (l>>3).
__global__ __launch_bounds__(256) void w4a16_gemm_lds(
    const uint4* __restrict__ xb, const uint4* __restrict__ wb,
    const float* __restrict__ bias, float* __restrict__ out) {

    __shared__ __align__(16) __bf16 As[BM * BK];
    __shared__ __align__(16) __bf16 Bs[BN * BK];

    const int tid  = threadIdx.x;
    const int lane = tid & 63;
    const int wid  = tid >> 6;
    const int wm   = wid >> 1;   // 0..1
    const int wn   = wid & 1;    // 0..1

    // XCD-aware swizzle (NWG=5504, 5504%8==0 -> bijective)
    int orig = blockIdx.x;
    int wg   = (orig & 7) * (NWG / 8) + (orig >> 3);
    const int bm0 = (wg / TILES_N) * BM;
    const int bn0 = (wg % TILES_N) * BN;

    // staging addresses: each wave covers rows [wid*32, wid*32+32) in 4 issues of 8 rows
    const int r8 = lane >> 3;              // row within 8-row group
    const int c8 = (lane & 7) ^ r8;        // pre-swizzled source chunk (involution)
    const uint4* gA = xb + (size_t)(bm0 + wid * 32 + r8) * (IN_F / 8) + c8;
    const uint4* gB = wb + (size_t)(bn0 + wid * 32 + r8) * (IN_F / 8) + c8;
    char* lA = (char*)As + (wid * 32) * (BK * 2);
    char* lB = (char*)Bs + (wid * 32) * (BK * 2);

    f32x4 acc[4][4];
#pragma unroll
    for (int i = 0; i < 4; ++i)
#pragma unroll
        for (int j = 0; j < 4; ++j) acc[i][j] = {0.f, 0.f, 0.f, 0.f};

    for (int kt = 0; kt < IN_F / BK; ++kt) {
        // ---- async stage: 4 issues A + 4 issues B per wave (1 KiB each) ----
#pragma unroll
        for (int i = 0; i < 4; ++i) {
            GLOAD_LDS16(gA + (size_t)i * 8 * (IN_F / 8) + kt * (BK / 8), lA + i * 8 * (BK * 2));
            GLOAD_LDS16(gB + (size_t)i * 8 * (IN_F / 8) + kt * (BK / 8), lB + i * 8 * (BK * 2));
        }
        __syncthreads();   // compiler emits s_waitcnt vmcnt(0) before s_barrier

        // ---- compute: 2 k-subtiles of 32, 16 MFMA each per wave ----
#pragma unroll
        for (int kk = 0; kk < 2; ++kk) {
            short8 a[4], b[4];
#pragma unroll
            for (int mi = 0; mi < 4; ++mi) {
                int row = wm * 64 + mi * 16 + (lane & 15);
                a[mi] = *(const short8*)((const char*)As + row * (BK * 2) +
                                         ((kk * 64 + (lane >> 4) * 16) ^ ((row & 7) << 4)));
            }
#pragma unroll
            for (int ni = 0; ni < 4; ++ni) {
                int row = wn * 64 + ni * 16 + (lane & 15);
                b[ni] = *(const short8*)((const char*)Bs + row * (BK * 2) +
                                         ((kk * 64 + (lane >> 4) * 16) ^ ((row & 7) << 4)));
            }
#pragma unroll
            for (int mi = 0; mi < 4; ++mi)
#pragma unroll
                for (int ni = 0; ni < 4; ++ni)
                    acc[mi][ni] = __builtin_amdgcn_mfma_f32_16x16x32_bf16(a[mi], b[ni], acc[mi][ni], 0, 0, 0);
        }
        __syncthreads();
    }

    // ---- epilogue: C/D layout col=lane&15, row=(lane>>4)*4+r ----
#pragma unroll
    for (int ni = 0; ni < 4; ++ni) {
        int col  = bn0 + wn * 64 + ni * 16 + (lane & 15);
        float bv = bias[col];
#pragma unroll
        for (int mi = 0; mi < 4; ++mi) {
            int row0 = bm0 + wm * 64 + mi * 16 + (lane >> 4) * 4;
#pragma unroll
            for (int r = 0; r < 4; ++r)
                out[(size_t)(row0 + r) * OUT_F + col] = acc[mi][ni][r] + bv;
        }
    }
}

// ---------- fallback (ws too small): R1 reg-staged kernel with inline dequant ----------
__global__ __launch_bounds__(256) void w4a16_gemm_fb(
    const float* __restrict__ xf,
    const int* __restrict__ pw,
    const float* __restrict__ scales, const int* __restrict__ zps,
    const float* __restrict__ bias, float* __restrict__ out) {

    __shared__ __align__(16) __bf16 As[BM * BK];
    __shared__ __align__(16) __bf16 Bs[BN * BK];

    const int tid  = threadIdx.x;
    const int lane = tid & 63;
    const int wid  = tid >> 6;
    const int wm   = wid >> 1;
    const int wn   = wid & 1;

    int orig = blockIdx.x;
    int wg   = (orig & 7) * (NWG / 8) + (orig >> 3);
    const int bm0 = (wg / TILES_N) * BM;
    const int bn0 = (wg % TILES_N) * BN;

    f32x4 acc[4][4];
#pragma unroll
    for (int i = 0; i < 4; ++i)
#pragma unroll
        for (int j = 0; j < 4; ++j) acc[i][j] = {0.f, 0.f, 0.f, 0.f};

    for (int kt = 0; kt < IN_F / BK; ++kt) {
#pragma unroll
        for (int i = 0; i < 4; ++i) {
            int ci  = i * 256 + tid;
            int row = ci >> 3, c8 = ci & 7;
            const float4* p = (const float4*)(xf + (size_t)(bm0 + row) * IN_F + kt * BK + c8 * 8);
            uint4 d = pack8_f(p[0], p[1]);
            *(uint4*)((char*)As + row * (BK * 2) + ((c8 * 16) ^ ((row & 7) << 4))) = d;
        }
#pragma unroll
        for (int i = 0; i < 4; ++i) {
            int ci  = i * 256 + tid;
            int row = ci >> 3, c8 = ci & 7;
            int r    = bn0 + row;
            float s  = scales[r];
            float zb = -s * (float)zps[r];
            int4 v = *(const int4*)(pw + (size_t)r * (IN_F / 2) + kt * (BK / 2) + c8 * 4);
            uint4 d = dequant8(v, s, zb);
            *(uint4*)((char*)Bs + row * (BK * 2) + ((c8 * 16) ^ ((row & 7) << 4))) = d;
        }
        __syncthreads();

#pragma unroll
        for (int kk = 0; kk < 2; ++kk) {
            short8 a[4], b[4];
#pragma unroll
            for (int mi = 0; mi < 4; ++mi) {
                int row = wm * 64 + mi * 16 + (lane & 15);
                a[mi] = *(const short8*)((const char*)As + row * (BK * 2) +
                                         ((kk * 64 + (lane >> 4) * 16) ^ ((row & 7) << 4)));
            }
#pragma unroll
            for (int ni = 0; ni < 4; ++ni) {
                int row = wn * 64 + ni * 16 + (lane & 15);
                b[ni] = *(const short8*)((const char*)Bs + row * (BK * 2) +
                                         ((kk * 64 + (lane >> 4) * 16) ^ ((row & 7) << 4)));
            }
#pragma unroll
            for (int mi = 0; mi < 4; ++mi)
#pragma unroll
                for (int ni = 0; ni < 4; ++ni)
                    acc[mi][ni] = __builtin_amdgcn_mfma_f32_16x16x32_bf16(a[mi], b[ni], acc[mi][ni], 0, 0, 0);
        }
        __syncthreads();
    }

#pragma unroll
    for (int ni = 0; ni < 4; ++ni) {
        int col  = bn0 + wn * 64 + ni * 16 + (lane & 15);
        float bv = bias[col];
#pragma unroll
        for (int mi = 0; mi < 4; ++mi) {
            int row0 = bm0 + wm * 64 + mi * 16 + (lane >> 4) * 4;
#pragma unroll
            for (int r = 0; r < 4; ++r)
                out[(size_t)(row0 + r) * OUT_F + col] = acc[mi][ni][r] + bv;
        }
    }
}

extern "C" void kernel_launch(void* const* d_in, const int* in_sizes, int n_in,
                              void* d_out, int out_size, void* d_ws, size_t ws_size,
                              hipStream_t stream) {
    const float* x      = (const float*)d_in[0];
    const int* pw       = (const int*)d_in[1];
    const float* scales = (const float*)d_in[2];
    const int* zps      = (const int*)d_in[3];
    const float* bias   = (const float*)d_in[4];
    float* out          = (float*)d_out;

    const size_t xb_bytes = (size_t)M_DIM * IN_F * 2;   // 64 MiB
    const size_t wb_bytes = (size_t)OUT_F * IN_F * 2;   // ~86 MiB
    const bool predeq = ws_size >= xb_bytes + wb_bytes;

    dim3 grid(NWG), block(256);
    if (predeq) {
        uint4* xb = (uint4*)d_ws;
        uint4* wb = (uint4*)((char*)d_ws + xb_bytes);
        cvt_x_kernel<<<2048, 256, 0, stream>>>(x, xb, M_DIM * IN_F / 8);
        deq_w_kernel<<<2048, 256, 0, stream>>>(pw, scales, zps, wb, OUT_F * (IN_F / 8));
        w4a16_gemm_lds<<<grid, block, 0, stream>>>(xb, wb, bias, out);
    } else {
        w4a16_gemm_fb<<<grid, block, 0, stream>>>(x, pw, scales, zps, bias, out);
    }
}

// Round 3
// 743.040 us; speedup vs baseline: 1.4797x; 1.4492x over previous
//
#include <hip/hip_runtime.h>
#include <hip/hip_bf16.h>
#include <stdint.h>

#define IN_F   4096
#define OUT_F  11008
#define M_DIM  8192          // B*S

// ---------------- 8-phase 256x256 geometry ----------------
#define BM 256
#define BN 256
#define BK 64
#define TM (M_DIM / BM)      // 32
#define TN (OUT_F / BN)      // 43
#define NWG (TM * TN)        // 1376, % 8 == 0 -> bijective XCD swizzle
#define KT (IN_F / BK)       // 64 K-tiles
#define KB (IN_F / 8)        // uint4 chunks per row (512)
#define HT_BYTES (128 * 64 * 2)   // one half-tile in LDS (16 KiB)

typedef __attribute__((ext_vector_type(8))) short short8;
typedef __attribute__((ext_vector_type(4))) float f32x4;

union Pack8 { __bf16 h[8]; uint4 u; };

__device__ inline uint4 pack8_f(float4 f0, float4 f1) {
    Pack8 o;
    o.h[0] = (__bf16)f0.x; o.h[1] = (__bf16)f0.y;
    o.h[2] = (__bf16)f0.z; o.h[3] = (__bf16)f0.w;
    o.h[4] = (__bf16)f1.x; o.h[5] = (__bf16)f1.y;
    o.h[6] = (__bf16)f1.z; o.h[7] = (__bf16)f1.w;
    return o.u;
}

__device__ inline uint4 dequant8(int4 v, float s, float zb) {
    Pack8 o;
    int pv[4] = {v.x, v.y, v.z, v.w};
#pragma unroll
    for (int j = 0; j < 4; ++j) {
        o.h[2 * j]     = (__bf16)fmaf((float)(pv[j] & 15), s, zb);
        o.h[2 * j + 1] = (__bf16)fmaf((float)((pv[j] >> 4) & 15), s, zb);
    }
    return o.u;
}

#define GLOAD_LDS16(g, l)                                                     \
    __builtin_amdgcn_global_load_lds(                                         \
        (const __attribute__((address_space(1))) void*)(g),                   \
        (__attribute__((address_space(3))) void*)(l), 16, 0, 0)

#define BAR() __builtin_amdgcn_s_barrier()
#define VMCNT4()                                                              \
    do {                                                                      \
        asm volatile("s_waitcnt vmcnt(4)" ::: "memory");                      \
        __builtin_amdgcn_sched_barrier(0);                                    \
    } while (0)

// ---------- preprocessing ----------
__global__ void cvt_x_kernel(const float* __restrict__ x, uint4* __restrict__ xb, int nChunks) {
    int stride = gridDim.x * blockDim.x;
    for (int c = blockIdx.x * blockDim.x + threadIdx.x; c < nChunks; c += stride) {
        const float4* p = (const float4*)(x + (size_t)c * 8);
        xb[c] = pack8_f(p[0], p[1]);
    }
}

__global__ void deq_w_kernel(const int* __restrict__ pw, const float* __restrict__ scales,
                             const int* __restrict__ zps, uint4* __restrict__ wb, int nChunks) {
    int stride = gridDim.x * blockDim.x;
    for (int c = blockIdx.x * blockDim.x + threadIdx.x; c < nChunks; c += stride) {
        int row = c >> 9;
        int cc  = c & 511;
        float s  = scales[row];
        float zb = -s * (float)zps[row];
        int4 v = *(const int4*)(pw + (size_t)row * (IN_F / 2) + cc * 4);
        wb[c] = dequant8(v, s, zb);
    }
}

// ---------- 8-phase helpers ----------
// LDS layout: byte offset of half-tile (buf, op{0=A,1=B}, h) = ((buf*2+op)*2+h)*HT_BYTES,
// each half-tile is [128 rows][64 bf16] with chunk swizzle slot = chunk ^ (row&7).
// gload_lds writes linearly; source chunk pre-swizzled: lane l covers row (base + l>>3),
// slot (l&7) <- global chunk (l&7)^(l>>3).

__device__ inline void stage_A(char* smem, const uint4* gA, int t, int h, int buf, int wid) {
    const uint4* s = gA + (size_t)h * 64 * KB + (size_t)(t & (KT - 1)) * (BK / 8);
    char* d = smem + ((buf * 2 + 0) * 2 + h) * HT_BYTES + (wid * 8) * 128;
    GLOAD_LDS16(s, d);
    GLOAD_LDS16(s + (size_t)128 * KB, d + 64 * 128);
}
__device__ inline void stage_B(char* smem, const uint4* gB, int t, int h, int buf, int wid) {
    const uint4* s = gB + (size_t)h * 32 * KB + (size_t)(t & (KT - 1)) * (BK / 8);
    char* d = smem + ((buf * 2 + 1) * 2 + h) * HT_BYTES + (wid * 8) * 128;
    GLOAD_LDS16(s, d);
    GLOAD_LDS16(s + (size_t)128 * KB, d + 64 * 128);
}

template <int QM>
__device__ inline void read_A(const char* smem, int buf, int wm, int lane, short8 (&a)[2][4]) {
    const char* base = smem + ((buf * 2 + 0) * 2 + QM) * HT_BYTES;
    const int r0 = wm * 64 + (lane & 15);
    const int cb = (lane >> 4) * 16;
#pragma unroll
    for (int mi = 0; mi < 4; ++mi) {
        int row = r0 + mi * 16;
#pragma unroll
        for (int kk = 0; kk < 2; ++kk)
            a[kk][mi] = *(const short8*)(base + row * 128 + ((kk * 64 + cb) ^ ((row & 7) << 4)));
    }
}

template <int QN>
__device__ inline void read_B(const char* smem, int buf, int wn, int lane, short8 (&bq)[2][2]) {
    const char* base = smem + ((buf * 2 + 1) * 2 + QN) * HT_BYTES;
    const int r0 = wn * 32 + (lane & 15);
    const int cb = (lane >> 4) * 16;
#pragma unroll
    for (int nj = 0; nj < 2; ++nj) {
        int row = r0 + nj * 16;
#pragma unroll
        for (int kk = 0; kk < 2; ++kk)
            bq[kk][nj] = *(const short8*)(base + row * 128 + ((kk * 64 + cb) ^ ((row & 7) << 4)));
    }
}

template <int QM, int QN>
__device__ inline void mfma16(short8 (&a)[2][4], short8 (&bq)[2][2], f32x4 (&acc)[2][4][2][2]) {
    __builtin_amdgcn_s_setprio(1);
#pragma unroll
    for (int kk = 0; kk < 2; ++kk)
#pragma unroll
        for (int mi = 0; mi < 4; ++mi)
#pragma unroll
            for (int nj = 0; nj < 2; ++nj)
                acc[QM][mi][QN][nj] = __builtin_amdgcn_mfma_f32_16x16x32_bf16(
                    a[kk][mi], bq[kk][nj], acc[QM][mi][QN][nj], 0, 0, 0);
    __builtin_amdgcn_s_setprio(0);
}

// ---------- the 8-phase 256x256 GEMM ----------
__global__ __launch_bounds__(512, 2) void w4a16_gemm8(
    const uint4* __restrict__ xb, const uint4* __restrict__ wb,
    const float* __restrict__ bias, float* __restrict__ out) {

    extern __shared__ __align__(16) char smem[];   // 128 KiB

    const int tid  = threadIdx.x;
    const int lane = tid & 63;
    const int wid  = tid >> 6;     // 0..7
    const int wm   = wid >> 2;     // 0..1
    const int wn   = wid & 3;      // 0..3

    int orig = blockIdx.x;
    int wg   = (orig & 7) * (NWG / 8) + (orig >> 3);
    const int bm0 = (wg / TN) * BM;
    const int bn0 = (wg % TN) * BN;

    // per-thread pre-swizzled global staging bases
    const int r8    = lane >> 3;
    const int chunk = (lane & 7) ^ r8;
    const uint4* gA = xb + (size_t)(bm0 + wid * 8 + r8) * KB + chunk;
    const uint4* gB = wb + (size_t)(bn0 + (wid >> 2) * 64 + (wid & 3) * 8 + r8) * KB + chunk;

    f32x4 acc[2][4][2][2];
#pragma unroll
    for (int qm = 0; qm < 2; ++qm)
#pragma unroll
        for (int mi = 0; mi < 4; ++mi)
#pragma unroll
            for (int qn = 0; qn < 2; ++qn)
#pragma unroll
                for (int nj = 0; nj < 2; ++nj) acc[qm][mi][qn][nj] = {0.f, 0.f, 0.f, 0.f};

    short8 a[2][4];      // current qm's A frags [kk][mi]
    short8 b[2][2][2];   // both qn's B frags   [qn][kk][nj]

    // prologue: tile0 (all 4 half-tiles -> buf0), tile1 (A0,B0 -> buf1)
    stage_A(smem, gA, 0, 0, 0, wid);
    stage_B(smem, gB, 0, 0, 0, wid);
    stage_A(smem, gA, 0, 1, 0, wid);
    stage_B(smem, gB, 0, 1, 0, wid);
    stage_A(smem, gA, 1, 0, 1, wid);
    stage_B(smem, gB, 1, 0, 1, wid);
    VMCNT4();            // tile0 fully landed; t1.A0/t1.B0 may be in flight
    BAR();

    for (int i = 0; i < KT / 2; ++i) {
        const int t1 = 2 * i + 1, t2 = 2 * i + 2, t3 = 2 * i + 3;
        // ---- P1: q(0,0) of buf0 ----
        read_A<0>(smem, 0, wm, lane, a);
        read_B<0>(smem, 0, wn, lane, b[0]);
        stage_A(smem, gA, t1, 1, 1, wid);
        BAR();
        mfma16<0, 0>(a, b[0], acc);
        BAR();
        // ---- P2: q(0,1) ----
        read_B<1>(smem, 0, wn, lane, b[1]);
        stage_B(smem, gB, t1, 1, 1, wid);
        BAR();
        mfma16<0, 1>(a, b[1], acc);
        BAR();
        // ---- P3: q(1,0) ----
        read_A<1>(smem, 0, wm, lane, a);
        stage_A(smem, gA, t2, 0, 0, wid);
        BAR();
        mfma16<1, 0>(a, b[0], acc);
        BAR();
        // ---- P4: q(1,1), vmcnt gate for buf1 ----
        stage_B(smem, gB, t2, 0, 0, wid);
        VMCNT4();
        BAR();
        mfma16<1, 1>(a, b[1], acc);
        BAR();
        // ---- P5: q(0,0) of buf1 ----
        read_A<0>(smem, 1, wm, lane, a);
        read_B<0>(smem, 1, wn, lane, b[0]);
        stage_A(smem, gA, t2, 1, 0, wid);
        BAR();
        mfma16<0, 0>(a, b[0], acc);
        BAR();
        // ---- P6: q(0,1) ----
        read_B<1>(smem, 1, wn, lane, b[1]);
        stage_B(smem, gB, t2, 1, 0, wid);
        BAR();
        mfma16<0, 1>(a, b[1], acc);
        BAR();
        // ---- P7: q(1,0) ----
        read_A<1>(smem, 1, wm, lane, a);
        stage_A(smem, gA, t3, 0, 1, wid);
        BAR();
        mfma16<1, 0>(a, b[0], acc);
        BAR();
        // ---- P8: q(1,1), vmcnt gate for buf0 ----
        stage_B(smem, gB, t3, 0, 1, wid);
        VMCNT4();
        BAR();
        mfma16<1, 1>(a, b[1], acc);
        BAR();
    }

    // ---- epilogue: C/D layout col=lane&15, row=(lane>>4)*4+rr ----
#pragma unroll
    for (int qm = 0; qm < 2; ++qm)
#pragma unroll
        for (int mi = 0; mi < 4; ++mi) {
            int row0 = bm0 + wm * 128 + qm * 64 + mi * 16 + (lane >> 4) * 4;
#pragma unroll
            for (int qn = 0; qn < 2; ++qn)
#pragma unroll
                for (int nj = 0; nj < 2; ++nj) {
                    int col  = bn0 + wn * 64 + qn * 32 + nj * 16 + (lane & 15);
                    float bv = bias[col];
#pragma unroll
                    for (int rr = 0; rr < 4; ++rr)
                        out[(size_t)(row0 + rr) * OUT_F + col] = acc[qm][mi][qn][nj][rr] + bv;
                }
        }
}

// ---------- fallback (ws too small): reg-staged 128^2 with inline dequant ----------
#define FBM 128
#define FBN 128
#define FTM (M_DIM / FBM)
#define FTN (OUT_F / FBN)
#define FNWG (FTM * FTN)

__global__ __launch_bounds__(256) void w4a16_gemm_fb(
    const float* __restrict__ xf,
    const int* __restrict__ pw,
    const float* __restrict__ scales, const int* __restrict__ zps,
    const float* __restrict__ bias, float* __restrict__ out) {

    __shared__ __align__(16) __bf16 As[FBM * 64];
    __shared__ __align__(16) __bf16 Bs[FBN * 64];

    const int tid  = threadIdx.x;
    const int lane = tid & 63;
    const int wid  = tid >> 6;
    const int wm   = wid >> 1;
    const int wn   = wid & 1;

    int orig = blockIdx.x;
    int wg   = (orig & 7) * (FNWG / 8) + (orig >> 3);
    const int bm0 = (wg / FTN) * FBM;
    const int bn0 = (wg % FTN) * FBN;

    f32x4 acc[4][4];
#pragma unroll
    for (int i = 0; i < 4; ++i)
#pragma unroll
        for (int j = 0; j < 4; ++j) acc[i][j] = {0.f, 0.f, 0.f, 0.f};

    for (int kt = 0; kt < IN_F / 64; ++kt) {
#pragma unroll
        for (int i = 0; i < 4; ++i) {
            int ci  = i * 256 + tid;
            int row = ci >> 3, c8 = ci & 7;
            const float4* p = (const float4*)(xf + (size_t)(bm0 + row) * IN_F + kt * 64 + c8 * 8);
            uint4 d = pack8_f(p[0], p[1]);
            *(uint4*)((char*)As + row * 128 + ((c8 * 16) ^ ((row & 7) << 4))) = d;
        }
#pragma unroll
        for (int i = 0; i < 4; ++i) {
            int ci  = i * 256 + tid;
            int row = ci >> 3, c8 = ci & 7;
            int r    = bn0 + row;
            float s  = scales[r];
            float zb = -s * (float)zps[r];
            int4 v = *(const int4*)(pw + (size_t)r * (IN_F / 2) + kt * 32 + c8 * 4);
            uint4 d = dequant8(v, s, zb);
            *(uint4*)((char*)Bs + row * 128 + ((c8 * 16) ^ ((row & 7) << 4))) = d;
        }
        __syncthreads();

#pragma unroll
        for (int kk = 0; kk < 2; ++kk) {
            short8 a[4], b[4];
#pragma unroll
            for (int mi = 0; mi < 4; ++mi) {
                int row = wm * 64 + mi * 16 + (lane & 15);
                a[mi] = *(const short8*)((const char*)As + row * 128 +
                                         ((kk * 64 + (lane >> 4) * 16) ^ ((row & 7) << 4)));
            }
#pragma unroll
            for (int ni = 0; ni < 4; ++ni) {
                int row = wn * 64 + ni * 16 + (lane & 15);
                b[ni] = *(const short8*)((const char*)Bs + row * 128 +
                                         ((kk * 64 + (lane >> 4) * 16) ^ ((row & 7) << 4)));
            }
#pragma unroll
            for (int mi = 0; mi < 4; ++mi)
#pragma unroll
                for (int ni = 0; ni < 4; ++ni)
                    acc[mi][ni] = __builtin_amdgcn_mfma_f32_16x16x32_bf16(a[mi], b[ni], acc[mi][ni], 0, 0, 0);
        }
        __syncthreads();
    }

#pragma unroll
    for (int ni = 0; ni < 4; ++ni) {
        int col  = bn0 + wn * 64 + ni * 16 + (lane & 15);
        float bv = bias[col];
#pragma unroll
        for (int mi = 0; mi < 4; ++mi) {
            int row0 = bm0 + wm * 64 + mi * 16 + (lane >> 4) * 4;
#pragma unroll
            for (int r = 0; r < 4; ++r)
                out[(size_t)(row0 + r) * OUT_F + col] = acc[mi][ni][r] + bv;
        }
    }
}

extern "C" void kernel_launch(void* const* d_in, const int* in_sizes, int n_in,
                              void* d_out, int out_size, void* d_ws, size_t ws_size,
                              hipStream_t stream) {
    const float* x      = (const float*)d_in[0];
    const int* pw       = (const int*)d_in[1];
    const float* scales = (const float*)d_in[2];
    const int* zps      = (const int*)d_in[3];
    const float* bias   = (const float*)d_in[4];
    float* out          = (float*)d_out;

    const size_t xb_bytes = (size_t)M_DIM * IN_F * 2;   // 64 MiB
    const size_t wb_bytes = (size_t)OUT_F * IN_F * 2;   // ~86 MiB
    const bool predeq = ws_size >= xb_bytes + wb_bytes;

    if (predeq) {
        uint4* xbuf = (uint4*)d_ws;
        uint4* wbuf = (uint4*)((char*)d_ws + xb_bytes);
        cvt_x_kernel<<<2048, 256, 0, stream>>>(x, xbuf, M_DIM * IN_F / 8);
        deq_w_kernel<<<2048, 256, 0, stream>>>(pw, scales, zps, wbuf, OUT_F * (IN_F / 8));
        (void)hipFuncSetAttribute((const void*)w4a16_gemm8,
                                  hipFuncAttributeMaxDynamicSharedMemorySize, 131072);
        w4a16_gemm8<<<dim3(NWG), dim3(512), 131072, stream>>>(xbuf, wbuf, bias, out);
    } else {
        w4a16_gemm_fb<<<dim3(FNWG), dim3(256), 0, stream>>>(x, pw, scales, zps, bias, out);
    }
}

// Round 4
// 704.209 us; speedup vs baseline: 1.5613x; 1.0551x over previous
//
#include <hip/hip_runtime.h>
#include <hip/hip_bf16.h>
#include <stdint.h>

#define IN_F   4096
#define OUT_F  11008
#define M_DIM  8192          // B*S

// ---------------- 8-phase 256x256 geometry ----------------
#define BM 256
#define BN 256
#define BK 64
#define TM (M_DIM / BM)      // 32
#define TN (OUT_F / BN)      // 43
#define NWG (TM * TN)        // 1376
#define KT (IN_F / BK)       // 64 K-tiles
#define KB (IN_F / 8)        // uint4 chunks per row (512)
#define HT_BYTES (128 * 64 * 2)   // one half-tile in LDS (16 KiB)

typedef __attribute__((ext_vector_type(8))) short short8;
typedef __attribute__((ext_vector_type(4))) float f32x4;

union Pack8 { __bf16 h[8]; uint4 u; };

__device__ inline uint4 pack8_f(float4 f0, float4 f1) {
    Pack8 o;
    o.h[0] = (__bf16)f0.x; o.h[1] = (__bf16)f0.y;
    o.h[2] = (__bf16)f0.z; o.h[3] = (__bf16)f0.w;
    o.h[4] = (__bf16)f1.x; o.h[5] = (__bf16)f1.y;
    o.h[6] = (__bf16)f1.z; o.h[7] = (__bf16)f1.w;
    return o.u;
}

__device__ inline uint4 dequant8(int4 v, float s, float zb) {
    Pack8 o;
    int pv[4] = {v.x, v.y, v.z, v.w};
#pragma unroll
    for (int j = 0; j < 4; ++j) {
        o.h[2 * j]     = (__bf16)fmaf((float)(pv[j] & 15), s, zb);
        o.h[2 * j + 1] = (__bf16)fmaf((float)((pv[j] >> 4) & 15), s, zb);
    }
    return o.u;
}

#define GLOAD_LDS16(g, l)                                                     \
    __builtin_amdgcn_global_load_lds(                                         \
        (const __attribute__((address_space(1))) void*)(g),                   \
        (__attribute__((address_space(3))) void*)(l), 16, 0, 0)

#define BAR() __builtin_amdgcn_s_barrier()
#define VMCNT4()                                                              \
    do {                                                                      \
        asm volatile("s_waitcnt vmcnt(4)" ::: "memory");                      \
        __builtin_amdgcn_sched_barrier(0);                                    \
    } while (0)

// ---------- preprocessing ----------
__global__ void cvt_x_kernel(const float* __restrict__ x, uint4* __restrict__ xb, int nChunks) {
    int stride = gridDim.x * blockDim.x;
    for (int c = blockIdx.x * blockDim.x + threadIdx.x; c < nChunks; c += stride) {
        const float4* p = (const float4*)(x + (size_t)c * 8);
        xb[c] = pack8_f(p[0], p[1]);
    }
}

__global__ void deq_w_kernel(const int* __restrict__ pw, const float* __restrict__ scales,
                             const int* __restrict__ zps, uint4* __restrict__ wb, int nChunks) {
    int stride = gridDim.x * blockDim.x;
    for (int c = blockIdx.x * blockDim.x + threadIdx.x; c < nChunks; c += stride) {
        int row = c >> 9;
        int cc  = c & 511;
        float s  = scales[row];
        float zb = -s * (float)zps[row];
        int4 v = *(const int4*)(pw + (size_t)row * (IN_F / 2) + cc * 4);
        wb[c] = dequant8(v, s, zb);
    }
}

// ---------- 8-phase helpers ----------
__device__ inline void stage_A(char* smem, const uint4* gA, int t, int h, int buf, int wid) {
    const uint4* s = gA + (size_t)h * 64 * KB + (size_t)(t & (KT - 1)) * (BK / 8);
    char* d = smem + ((buf * 2 + 0) * 2 + h) * HT_BYTES + (wid * 8) * 128;
    GLOAD_LDS16(s, d);
    GLOAD_LDS16(s + (size_t)128 * KB, d + 64 * 128);
}
__device__ inline void stage_B(char* smem, const uint4* gB, int t, int h, int buf, int wid) {
    const uint4* s = gB + (size_t)h * 32 * KB + (size_t)(t & (KT - 1)) * (BK / 8);
    char* d = smem + ((buf * 2 + 1) * 2 + h) * HT_BYTES + (wid * 8) * 128;
    GLOAD_LDS16(s, d);
    GLOAD_LDS16(s + (size_t)128 * KB, d + 64 * 128);
}

template <int QM>
__device__ inline void read_A(const char* smem, int buf, int wm, int lane, short8 (&a)[2][4]) {
    const char* base = smem + ((buf * 2 + 0) * 2 + QM) * HT_BYTES;
    const int r0 = wm * 64 + (lane & 15);
    const int cb = (lane >> 4) * 16;
#pragma unroll
    for (int mi = 0; mi < 4; ++mi) {
        int row = r0 + mi * 16;
#pragma unroll
        for (int kk = 0; kk < 2; ++kk)
            a[kk][mi] = *(const short8*)(base + row * 128 + ((kk * 64 + cb) ^ ((row & 7) << 4)));
    }
}

template <int QN>
__device__ inline void read_B(const char* smem, int buf, int wn, int lane, short8 (&bq)[2][2]) {
    const char* base = smem + ((buf * 2 + 1) * 2 + QN) * HT_BYTES;
    const int r0 = wn * 32 + (lane & 15);
    const int cb = (lane >> 4) * 16;
#pragma unroll
    for (int nj = 0; nj < 2; ++nj) {
        int row = r0 + nj * 16;
#pragma unroll
        for (int kk = 0; kk < 2; ++kk)
            bq[kk][nj] = *(const short8*)(base + row * 128 + ((kk * 64 + cb) ^ ((row & 7) << 4)));
    }
}

template <int QM, int QN>
__device__ inline void mfma16(short8 (&a)[2][4], short8 (&bq)[2][2], f32x4 (&acc)[2][4][2][2]) {
    __builtin_amdgcn_s_setprio(1);
#pragma unroll
    for (int kk = 0; kk < 2; ++kk)
#pragma unroll
        for (int mi = 0; mi < 4; ++mi)
#pragma unroll
            for (int nj = 0; nj < 2; ++nj)
                acc[QM][mi][QN][nj] = __builtin_amdgcn_mfma_f32_16x16x32_bf16(
                    a[kk][mi], bq[kk][nj], acc[QM][mi][QN][nj], 0, 0, 0);
    __builtin_amdgcn_s_setprio(0);
}

// ---------- the 8-phase 256x256 GEMM ----------
__global__ __launch_bounds__(512, 2) void w4a16_gemm8(
    const uint4* __restrict__ xb, const uint4* __restrict__ wb,
    const float* __restrict__ bias, float* __restrict__ out) {

    extern __shared__ __align__(16) char smem[];   // 128 KiB

    const int tid  = threadIdx.x;
    const int lane = tid & 63;
    const int wid  = tid >> 6;     // 0..7
    const int wm   = wid >> 2;     // 0..1
    const int wn   = wid & 3;      // 0..3

    // 2-D supertile mapping: XCD (bid&7) owns m-tile rows [4*xcd, 4*xcd+4);
    // within an XCD, walk 4m x 4n supertiles left-to-right (ragged last col of 3).
    // Concurrent working set: all of A (64 MB, L3-resident) + sliding ~8-wide B window.
    const int bid = blockIdx.x;
    const int xcd = bid & 7;
    const int p   = bid >> 3;          // 0..171
    int tm, tn;
    if (p < 160) { int c = p >> 4, q = p & 15; tm = xcd * 4 + (q & 3); tn = c * 4 + (q >> 2); }
    else         { int q = p - 160;            tm = xcd * 4 + (q & 3); tn = 40 + (q >> 2); }
    const int bm0 = tm * BM;
    const int bn0 = tn * BN;

    // per-thread pre-swizzled global staging bases
    const int r8    = lane >> 3;
    const int chunk = (lane & 7) ^ r8;
    const uint4* gA = xb + (size_t)(bm0 + wid * 8 + r8) * KB + chunk;
    const uint4* gB = wb + (size_t)(bn0 + (wid >> 2) * 64 + (wid & 3) * 8 + r8) * KB + chunk;

    f32x4 acc[2][4][2][2];
#pragma unroll
    for (int qm = 0; qm < 2; ++qm)
#pragma unroll
        for (int mi = 0; mi < 4; ++mi)
#pragma unroll
            for (int qn = 0; qn < 2; ++qn)
#pragma unroll
                for (int nj = 0; nj < 2; ++nj) acc[qm][mi][qn][nj] = {0.f, 0.f, 0.f, 0.f};

    short8 a[2][4];      // current qm's A frags [kk][mi]
    short8 b[2][2][2];   // both qn's B frags   [qn][kk][nj]

    // prologue: tile0 (all 4 half-tiles -> buf0), tile1 (A0,B0 -> buf1)
    stage_A(smem, gA, 0, 0, 0, wid);
    stage_B(smem, gB, 0, 0, 0, wid);
    stage_A(smem, gA, 0, 1, 0, wid);
    stage_B(smem, gB, 0, 1, 0, wid);
    stage_A(smem, gA, 1, 0, 1, wid);
    stage_B(smem, gB, 1, 0, 1, wid);
    VMCNT4();            // tile0 fully landed; t1.A0/t1.B0 may be in flight
    BAR();

    for (int i = 0; i < KT / 2; ++i) {
        const int t1 = 2 * i + 1, t2 = 2 * i + 2, t3 = 2 * i + 3;
        // ---- P1: q(0,0) of buf0 ----
        read_A<0>(smem, 0, wm, lane, a);
        read_B<0>(smem, 0, wn, lane, b[0]);
        stage_A(smem, gA, t1, 1, 1, wid);
        BAR();
        mfma16<0, 0>(a, b[0], acc);
        BAR();
        // ---- P2: q(0,1) ----
        read_B<1>(smem, 0, wn, lane, b[1]);
        stage_B(smem, gB, t1, 1, 1, wid);
        BAR();
        mfma16<0, 1>(a, b[1], acc);
        BAR();
        // ---- P3: q(1,0) ----
        read_A<1>(smem, 0, wm, lane, a);
        stage_A(smem, gA, t2, 0, 0, wid);
        BAR();
        mfma16<1, 0>(a, b[0], acc);
        BAR();
        // ---- P4: q(1,1), vmcnt gate for buf1 ----
        stage_B(smem, gB, t2, 0, 0, wid);
        VMCNT4();
        BAR();
        mfma16<1, 1>(a, b[1], acc);
        BAR();
        // ---- P5: q(0,0) of buf1 ----
        read_A<0>(smem, 1, wm, lane, a);
        read_B<0>(smem, 1, wn, lane, b[0]);
        stage_A(smem, gA, t2, 1, 0, wid);
        BAR();
        mfma16<0, 0>(a, b[0], acc);
        BAR();
        // ---- P6: q(0,1) ----
        read_B<1>(smem, 1, wn, lane, b[1]);
        stage_B(smem, gB, t2, 1, 0, wid);
        BAR();
        mfma16<0, 1>(a, b[1], acc);
        BAR();
        // ---- P7: q(1,0) ----
        read_A<1>(smem, 1, wm, lane, a);
        stage_A(smem, gA, t3, 0, 1, wid);
        BAR();
        mfma16<1, 0>(a, b[0], acc);
        BAR();
        // ---- P8: q(1,1), vmcnt gate for buf0 ----
        stage_B(smem, gB, t3, 0, 1, wid);
        VMCNT4();
        BAR();
        mfma16<1, 1>(a, b[1], acc);
        BAR();
    }

    // ---- epilogue: C/D layout col=lane&15, row=(lane>>4)*4+rr; nontemporal f32 stores ----
#pragma unroll
    for (int qm = 0; qm < 2; ++qm)
#pragma unroll
        for (int mi = 0; mi < 4; ++mi) {
            int row0 = bm0 + wm * 128 + qm * 64 + mi * 16 + (lane >> 4) * 4;
#pragma unroll
            for (int qn = 0; qn < 2; ++qn)
#pragma unroll
                for (int nj = 0; nj < 2; ++nj) {
                    int col  = bn0 + wn * 64 + qn * 32 + nj * 16 + (lane & 15);
                    float bv = bias[col];
#pragma unroll
                    for (int rr = 0; rr < 4; ++rr)
                        __builtin_nontemporal_store(acc[qm][mi][qn][nj][rr] + bv,
                                                    &out[(size_t)(row0 + rr) * OUT_F + col]);
                }
        }
}

// ---------- fallback (ws too small): reg-staged 128^2 with inline dequant ----------
#define FBM 128
#define FBN 128
#define FTM (M_DIM / FBM)
#define FTN (OUT_F / FBN)
#define FNWG (FTM * FTN)

__global__ __launch_bounds__(256) void w4a16_gemm_fb(
    const float* __restrict__ xf,
    const int* __restrict__ pw,
    const float* __restrict__ scales, const int* __restrict__ zps,
    const float* __restrict__ bias, float* __restrict__ out) {

    __shared__ __align__(16) __bf16 As[FBM * 64];
    __shared__ __align__(16) __bf16 Bs[FBN * 64];

    const int tid  = threadIdx.x;
    const int lane = tid & 63;
    const int wid  = tid >> 6;
    const int wm   = wid >> 1;
    const int wn   = wid & 1;

    int orig = blockIdx.x;
    int wg   = (orig & 7) * (FNWG / 8) + (orig >> 3);
    const int bm0 = (wg / FTN) * FBM;
    const int bn0 = (wg % FTN) * FBN;

    f32x4 acc[4][4];
#pragma unroll
    for (int i = 0; i < 4; ++i)
#pragma unroll
        for (int j = 0; j < 4; ++j) acc[i][j] = {0.f, 0.f, 0.f, 0.f};

    for (int kt = 0; kt < IN_F / 64; ++kt) {
#pragma unroll
        for (int i = 0; i < 4; ++i) {
            int ci  = i * 256 + tid;
            int row = ci >> 3, c8 = ci & 7;
            const float4* p = (const float4*)(xf + (size_t)(bm0 + row) * IN_F + kt * 64 + c8 * 8);
            uint4 d = pack8_f(p[0], p[1]);
            *(uint4*)((char*)As + row * 128 + ((c8 * 16) ^ ((row & 7) << 4))) = d;
        }
#pragma unroll
        for (int i = 0; i < 4; ++i) {
            int ci  = i * 256 + tid;
            int row = ci >> 3, c8 = ci & 7;
            int r    = bn0 + row;
            float s  = scales[r];
            float zb = -s * (float)zps[r];
            int4 v = *(const int4*)(pw + (size_t)r * (IN_F / 2) + kt * 32 + c8 * 4);
            uint4 d = dequant8(v, s, zb);
            *(uint4*)((char*)Bs + row * 128 + ((c8 * 16) ^ ((row & 7) << 4))) = d;
        }
        __syncthreads();

#pragma unroll
        for (int kk = 0; kk < 2; ++kk) {
            short8 a[4], b[4];
#pragma unroll
            for (int mi = 0; mi < 4; ++mi) {
                int row = wm * 64 + mi * 16 + (lane & 15);
                a[mi] = *(const short8*)((const char*)As + row * 128 +
                                         ((kk * 64 + (lane >> 4) * 16) ^ ((row & 7) << 4)));
            }
#pragma unroll
            for (int ni = 0; ni < 4; ++ni) {
                int row = wn * 64 + ni * 16 + (lane & 15);
                b[ni] = *(const short8*)((const char*)Bs + row * 128 +
                                         ((kk * 64 + (lane >> 4) * 16) ^ ((row & 7) << 4)));
            }
#pragma unroll
            for (int mi = 0; mi < 4; ++mi)
#pragma unroll
                for (int ni = 0; ni < 4; ++ni)
                    acc[mi][ni] = __builtin_amdgcn_mfma_f32_16x16x32_bf16(a[mi], b[ni], acc[mi][ni], 0, 0, 0);
        }
        __syncthreads();
    }

#pragma unroll
    for (int ni = 0; ni < 4; ++ni) {
        int col  = bn0 + wn * 64 + ni * 16 + (lane & 15);
        float bv = bias[col];
#pragma unroll
        for (int mi = 0; mi < 4; ++mi) {
            int row0 = bm0 + wm * 64 + mi * 16 + (lane >> 4) * 4;
#pragma unroll
            for (int r = 0; r < 4; ++r)
                out[(size_t)(row0 + r) * OUT_F + col] = acc[mi][ni][r] + bv;
        }
    }
}

extern "C" void kernel_launch(void* const* d_in, const int* in_sizes, int n_in,
                              void* d_out, int out_size, void* d_ws, size_t ws_size,
                              hipStream_t stream) {
    const float* x      = (const float*)d_in[0];
    const int* pw       = (const int*)d_in[1];
    const float* scales = (const float*)d_in[2];
    const int* zps      = (const int*)d_in[3];
    const float* bias   = (const float*)d_in[4];
    float* out          = (float*)d_out;

    const size_t xb_bytes = (size_t)M_DIM * IN_F * 2;   // 64 MiB
    const size_t wb_bytes = (size_t)OUT_F * IN_F * 2;   // ~86 MiB
    const bool predeq = ws_size >= xb_bytes + wb_bytes;

    if (predeq) {
        uint4* xbuf = (uint4*)d_ws;
        uint4* wbuf = (uint4*)((char*)d_ws + xb_bytes);
        cvt_x_kernel<<<2048, 256, 0, stream>>>(x, xbuf, M_DIM * IN_F / 8);
        deq_w_kernel<<<2048, 256, 0, stream>>>(pw, scales, zps, wbuf, OUT_F * (IN_F / 8));
        (void)hipFuncSetAttribute((const void*)w4a16_gemm8,
                                  hipFuncAttributeMaxDynamicSharedMemorySize, 131072);
        w4a16_gemm8<<<dim3(NWG), dim3(512), 131072, stream>>>(xbuf, wbuf, bias, out);
    } else {
        w4a16_gemm_fb<<<dim3(FNWG), dim3(256), 0, stream>>>(x, pw, scales, zps, bias, out);
    }
}